// Round 1
// baseline (52.450 us; speedup 1.0000x reference)
//
#include <hip/hip_runtime.h>
#include <math.h>

// Problem constants (from reference setup_inputs): b=64, seq=2048, hid=256
#define BATCH 64
#define SEQ   2048
#define HID   256
#define KNEG  63            // b - 1

// loss denominator: b*200*(K+1)*4 = 64*200*64*4 = 3,276,800
#define INV_DENOM (1.0f / 3276800.0f)

// Per-s kernel: block s computes
//   D[s]  = sum_i <rs_n[i,s], rt_n[i,s]>
//   S[s]  = sum_i rs_n[i,s,:]
//   T[s]  = sum_i rt_n[i,s,:]
//   partial[s] = (2*b - (1.5 + 1/(2K))*D + <S,T>/(2K)) / denom
__global__ __launch_bounds__(256) void cosnce_per_s(
    const float* __restrict__ rs, const float* __restrict__ rt,
    float* __restrict__ partial) {
  const int s    = blockIdx.x;      // 0..SEQ-1
  const int tid  = threadIdx.x;     // 0..255
  const int wave = tid >> 6;        // 0..3
  const int lane = tid & 63;        // 0..63

  __shared__ float S_sh[4][HID];
  __shared__ float T_sh[4][HID];
  __shared__ float D_sh[4];
  __shared__ float red_sh[4];

  // lane l owns hid elements [4l, 4l+3]
  float S0 = 0.f, S1 = 0.f, S2 = 0.f, S3 = 0.f;
  float T0 = 0.f, T1 = 0.f, T2 = 0.f, T3 = 0.f;
  float D  = 0.f;

  const size_t col = (size_t)lane * 4;

#pragma unroll 4
  for (int ii = 0; ii < 16; ++ii) {
    const int i = wave * 16 + ii;   // this wave's batch row
    const size_t base = ((size_t)i * SEQ + s) * HID + col;
    const float4 a = *(const float4*)(rs + base);
    const float4 b = *(const float4*)(rt + base);

    float ss = a.x * a.x + a.y * a.y + a.z * a.z + a.w * a.w;
    float tt = b.x * b.x + b.y * b.y + b.z * b.z + b.w * b.w;
    float st = a.x * b.x + a.y * b.y + a.z * b.z + a.w * b.w;

    // wave-level butterfly reductions (64 lanes), no syncthreads
#pragma unroll
    for (int off = 32; off > 0; off >>= 1) {
      ss += __shfl_xor(ss, off);
      tt += __shfl_xor(tt, off);
      st += __shfl_xor(st, off);
    }

    // F.normalize semantics: x / max(||x||, eps), eps = 1e-12
    const float inv_s = 1.f / fmaxf(sqrtf(ss), 1e-12f);
    const float inv_t = 1.f / fmaxf(sqrtf(tt), 1e-12f);

    D  += st * inv_s * inv_t;  // identical across lanes after butterfly
    S0 += a.x * inv_s; S1 += a.y * inv_s; S2 += a.z * inv_s; S3 += a.w * inv_s;
    T0 += b.x * inv_t; T1 += b.y * inv_t; T2 += b.z * inv_t; T3 += b.w * inv_t;
  }

  // stash per-wave partial S/T vectors + D into LDS
  *(float4*)&S_sh[wave][col] = make_float4(S0, S1, S2, S3);
  *(float4*)&T_sh[wave][col] = make_float4(T0, T1, T2, T3);
  if (lane == 0) D_sh[wave] = D;
  __syncthreads();

  // thread t combines hid element t across the 4 waves, then block-reduce <S,T>
  float Ssum = S_sh[0][tid] + S_sh[1][tid] + S_sh[2][tid] + S_sh[3][tid];
  float Tsum = T_sh[0][tid] + T_sh[1][tid] + T_sh[2][tid] + T_sh[3][tid];
  float prod = Ssum * Tsum;
#pragma unroll
  for (int off = 32; off > 0; off >>= 1) prod += __shfl_xor(prod, off);
  if (lane == 0) red_sh[wave] = prod;
  __syncthreads();

  if (tid == 0) {
    const float STdot = red_sh[0] + red_sh[1] + red_sh[2] + red_sh[3];
    const float Dtot  = D_sh[0] + D_sh[1] + D_sh[2] + D_sh[3];
    const float inv2K = 1.f / (2.f * (float)KNEG);
    const float c = 2.f * (float)BATCH - (1.5f + inv2K) * Dtot + STdot * inv2K;
    partial[s] = c * INV_DENOM;
  }
}

// Deterministic final reduction of SEQ partials -> scalar loss.
__global__ __launch_bounds__(256) void cosnce_reduce(
    const float* __restrict__ partial, float* __restrict__ out) {
  const int tid  = threadIdx.x;
  const int wave = tid >> 6;
  const int lane = tid & 63;
  float acc = 0.f;
  for (int idx = tid; idx < SEQ; idx += 256) acc += partial[idx];
#pragma unroll
  for (int off = 32; off > 0; off >>= 1) acc += __shfl_xor(acc, off);
  __shared__ float sh[4];
  if (lane == 0) sh[wave] = acc;
  __syncthreads();
  if (tid == 0) out[0] = sh[0] + sh[1] + sh[2] + sh[3];
}

extern "C" void kernel_launch(void* const* d_in, const int* in_sizes, int n_in,
                              void* d_out, int out_size, void* d_ws, size_t ws_size,
                              hipStream_t stream) {
  const float* rs = (const float*)d_in[0];   // r_s [64,2048,256] fp32
  const float* rt = (const float*)d_in[1];   // r_t [64,2048,256] fp32
  float* out      = (float*)d_out;           // scalar fp32 loss
  float* partial  = (float*)d_ws;            // SEQ floats of scratch

  cosnce_per_s<<<SEQ, 256, 0, stream>>>(rs, rt, partial);
  cosnce_reduce<<<1, 256, 0, stream>>>(partial, out);
}